// Round 2
// baseline (29309.955 us; speedup 1.0000x reference)
//
#include <hip/hip_runtime.h>

#define HID 64
#define EPB 8      // batch elements per wave-team
#define HSTR 68    // padded dwords per h row (16B-aligned, bank-spread)

#define LOG2E 1.44269504088896340736f

__device__ __forceinline__ float fast_sigmoid(float x) {
    // 1/(1+2^(-x*log2e)) ; v_exp_f32 + v_rcp_f32, ~1 ulp each
    float t = __builtin_amdgcn_exp2f(-x * LOG2E);
    return __builtin_amdgcn_rcpf(1.f + t);
}
__device__ __forceinline__ float fast_tanh(float x) {
    // 1 - 2/(1+2^(2x*log2e))
    float t = __builtin_amdgcn_exp2f(x * (2.f * LOG2E));
    return 1.f - 2.f * __builtin_amdgcn_rcpf(1.f + t);
}

__global__ __launch_bounds__(64, 1)
void gru_traj_kernel(const float* __restrict__ z0,
                     const float* __restrict__ dtp,
                     const int* __restrict__ stepsp,
                     const float* __restrict__ Wih,
                     const float* __restrict__ Whh,
                     const float* __restrict__ bih,
                     const float* __restrict__ bhh,
                     const float* __restrict__ Whead,
                     const float* __restrict__ bhead,
                     float* __restrict__ out)
{
    __shared__ __align__(16) float hbuf[EPB * HSTR];
    __shared__ float wh_lds[3 * HID];
    __shared__ float zbuf[EPB * 4];

    const int  lane   = threadIdx.x;          // 0..63 == hidden unit index
    const long blk    = blockIdx.x;
    const float dt    = dtp[0];
    const int nsteps  = stepsp[0];

    // ---- stage W_hh rows for this lane's unit (3 gates) into registers ----
    float wr[HID], wu[HID], wn[HID];
    {
        const float4* Wr4 = (const float4*)(Whh + (0*HID + lane)*HID);
        const float4* Wu4 = (const float4*)(Whh + (1*HID + lane)*HID);
        const float4* Wn4 = (const float4*)(Whh + (2*HID + lane)*HID);
        #pragma unroll
        for (int q = 0; q < HID/4; ++q) {
            float4 a = Wr4[q]; wr[4*q+0]=a.x; wr[4*q+1]=a.y; wr[4*q+2]=a.z; wr[4*q+3]=a.w;
            float4 b = Wu4[q]; wu[4*q+0]=b.x; wu[4*q+1]=b.y; wu[4*q+2]=b.z; wu[4*q+3]=b.w;
            float4 c = Wn4[q]; wn[4*q+0]=c.x; wn[4*q+1]=c.y; wn[4*q+2]=c.z; wn[4*q+3]=c.w;
        }
    }
    // W_ih rows for this unit (3 gates x d=3)
    const float wir0 = Wih[(0*HID+lane)*3+0], wir1 = Wih[(0*HID+lane)*3+1], wir2 = Wih[(0*HID+lane)*3+2];
    const float wiu0 = Wih[(1*HID+lane)*3+0], wiu1 = Wih[(1*HID+lane)*3+1], wiu2 = Wih[(1*HID+lane)*3+2];
    const float win0 = Wih[(2*HID+lane)*3+0], win1 = Wih[(2*HID+lane)*3+1], win2 = Wih[(2*HID+lane)*3+2];
    // biases: r/u combine; n keeps b_ih_n and b_hh_n separate (r multiplies b_hh_n)
    const float br   = bih[0*HID+lane] + bhh[0*HID+lane];
    const float bu   = bih[1*HID+lane] + bhh[1*HID+lane];
    const float bin_ = bih[2*HID+lane];
    const float bhn  = bhh[2*HID+lane];
    const float bh0 = bhead[0], bh1 = bhead[1], bh2 = bhead[2];

    // W_head -> LDS (per-lane coalesced copy)
    #pragma unroll
    for (int c = 0; c < 3; ++c) wh_lds[c*HID + lane] = Whead[c*HID + lane];

    // init h = 0
    #pragma unroll
    for (int e = 0; e < EPB; ++e) hbuf[e*HSTR + lane] = 0.f;

    // init z (lanes 0..7 own one elem each), write traj row t=0
    float zr0 = 0.f, zr1 = 0.f, zr2 = 0.f;
    float* op = out;  // per-lane output cursor (only lanes <EPB use it)
    if (lane < EPB) {
        const long eg = blk*EPB + lane;
        zr0 = z0[eg*3+0]; zr1 = z0[eg*3+1]; zr2 = z0[eg*3+2];
        zbuf[lane*4+0] = zr0; zbuf[lane*4+1] = zr1; zbuf[lane*4+2] = zr2;
        op = out + (size_t)eg * (size_t)(nsteps+1) * 3;
        op[0] = zr0; op[1] = zr1; op[2] = zr2;
        op += 3;
    }
    // single wave per workgroup: DS pipe is in-order per wave -> no barriers needed

    const int e2 = lane & 7;    // phase-2: elem
    const int g2 = lane >> 3;   // phase-2: unit-group

    #pragma unroll 1
    for (int t = 0; t < nsteps; ++t) {
        // ---------- phase 1: GRU cell for each of the 8 elems ----------
        #pragma unroll 1
        for (int e = 0; e < EPB; ++e) {
            // 6 accumulator chains for ILP
            float ar0 = br,  ar1 = 0.f;
            float au0 = bu,  au1 = 0.f;
            float an0 = bhn, an1 = 0.f;
            const float4* h4 = (const float4*)&hbuf[e*HSTR];
            #pragma unroll
            for (int q = 0; q < HID/4; q += 2) {
                float4 ha = h4[q];
                ar0 += wr[4*q+0]*ha.x; ar0 += wr[4*q+1]*ha.y; ar0 += wr[4*q+2]*ha.z; ar0 += wr[4*q+3]*ha.w;
                au0 += wu[4*q+0]*ha.x; au0 += wu[4*q+1]*ha.y; au0 += wu[4*q+2]*ha.z; au0 += wu[4*q+3]*ha.w;
                an0 += wn[4*q+0]*ha.x; an0 += wn[4*q+1]*ha.y; an0 += wn[4*q+2]*ha.z; an0 += wn[4*q+3]*ha.w;
                float4 hb = h4[q+1];
                ar1 += wr[4*q+4]*hb.x; ar1 += wr[4*q+5]*hb.y; ar1 += wr[4*q+6]*hb.z; ar1 += wr[4*q+7]*hb.w;
                au1 += wu[4*q+4]*hb.x; au1 += wu[4*q+5]*hb.y; au1 += wu[4*q+6]*hb.z; au1 += wu[4*q+7]*hb.w;
                an1 += wn[4*q+4]*hb.x; an1 += wn[4*q+5]*hb.y; an1 += wn[4*q+6]*hb.z; an1 += wn[4*q+7]*hb.w;
            }
            const float ze0 = zbuf[e*4+0], ze1 = zbuf[e*4+1], ze2 = zbuf[e*4+2];
            float ar = ar0 + ar1 + (wir0*ze0 + wir1*ze1 + wir2*ze2);
            float au = au0 + au1 + (wiu0*ze0 + wiu1*ze1 + wiu2*ze2);
            float ahn = an0 + an1;
            float ain = bin_ + (win0*ze0 + win1*ze1 + win2*ze2);

            float r = fast_sigmoid(ar);
            float u = fast_sigmoid(au);
            float n = fast_tanh(ain + r*ahn);

            float hold = hbuf[e*HSTR + lane];
            float hnew = n + u*(hold - n);      // == (1-u)*n + u*h
            hbuf[e*HSTR + lane] = hnew;
        }

        // ---------- phase 2: f_hat = W_head @ h_new, z update, traj write ----------
        float p0 = 0.f, p1 = 0.f, p2 = 0.f;
        #pragma unroll
        for (int jj = 0; jj < 8; ++jj) {
            const int j = 8*g2 + jj;
            const float hv = hbuf[e2*HSTR + j];
            p0 += wh_lds[0*HID + j]*hv;
            p1 += wh_lds[1*HID + j]*hv;
            p2 += wh_lds[2*HID + j]*hv;
        }
        #pragma unroll
        for (int m = 8; m < 64; m <<= 1) {
            p0 += __shfl_xor(p0, m);
            p1 += __shfl_xor(p1, m);
            p2 += __shfl_xor(p2, m);
        }
        if (g2 == 0) {
            zr0 += dt*(p0 + bh0);
            zr1 += dt*(p1 + bh1);
            zr2 += dt*(p2 + bh2);
            zbuf[lane*4+0] = zr0; zbuf[lane*4+1] = zr1; zbuf[lane*4+2] = zr2;
            op[0] = zr0; op[1] = zr1; op[2] = zr2;
            op += 3;
        }
    }
}

extern "C" void kernel_launch(void* const* d_in, const int* in_sizes, int n_in,
                              void* d_out, int out_size, void* d_ws, size_t ws_size,
                              hipStream_t stream) {
    const float* z0    = (const float*)d_in[0];
    const float* dtp   = (const float*)d_in[1];
    const int*   steps = (const int*)  d_in[2];
    const float* Wih   = (const float*)d_in[3];
    const float* Whh   = (const float*)d_in[4];
    const float* bih   = (const float*)d_in[5];
    const float* bhh   = (const float*)d_in[6];
    const float* Whead = (const float*)d_in[7];
    const float* bhead = (const float*)d_in[8];
    float* out = (float*)d_out;

    const int B = in_sizes[0] / 3;          // 16384
    const int nblk = B / EPB;               // 2048 blocks x 64 threads

    hipLaunchKernelGGL(gru_traj_kernel, dim3(nblk), dim3(64), 0, stream,
                       z0, dtp, steps, Wih, Whh, bih, bhh, Whead, bhead, out);
}

// Round 3
// 14212.157 us; speedup vs baseline: 2.0623x; 2.0623x over previous
//
#include <hip/hip_runtime.h>

typedef short short8 __attribute__((ext_vector_type(8)));
typedef float f32x4 __attribute__((ext_vector_type(4)));

#define LOG2E 1.44269504088896340736f
#define MELEM 32          // batch elems per block (2 M-tiles of 16)
#define HS 72             // u16 stride of h LDS rows (16B-aligned, bank-spread)

__device__ __forceinline__ float fast_sigmoid(float x) {
    float t = __builtin_amdgcn_exp2f(-x * LOG2E);
    return __builtin_amdgcn_rcpf(1.f + t);
}
__device__ __forceinline__ float fast_tanh(float x) {
    float t = __builtin_amdgcn_exp2f(x * (2.f * LOG2E));
    return 1.f - 2.f * __builtin_amdgcn_rcpf(1.f + t);
}
__device__ __forceinline__ unsigned bf16r(float x) {   // RNE float->bf16 bits
    unsigned u = __builtin_bit_cast(unsigned, x);
    return (u + 0x7fffu + ((u >> 16) & 1u)) >> 16;
}
__device__ __forceinline__ float bf16f(unsigned b) {
    return __builtin_bit_cast(float, b << 16);
}

__global__ __launch_bounds__(256, 2)
void gru_mfma_kernel(const float* __restrict__ z0,
                     const float* __restrict__ dtp,
                     const int* __restrict__ stepsp,
                     const float* __restrict__ Wih,
                     const float* __restrict__ Whh,
                     const float* __restrict__ bih,
                     const float* __restrict__ bhh,
                     const float* __restrict__ Whead,
                     const float* __restrict__ bhead,
                     float* __restrict__ out)
{
    __shared__ __align__(16) ushort hhi[MELEM*HS];
    __shared__ __align__(16) ushort hmi[MELEM*HS];
    __shared__ __align__(16) ushort hlo[MELEM*HS];
    __shared__ float zsh[MELEM*4];

    const int tid = threadIdx.x;
    const int w   = tid >> 6;       // wave 0..3 -> unit range [16w,16w+16)
    const int l   = tid & 63;
    const int c16 = l & 15;
    const int g   = l >> 4;         // 0..3
    const int unit = 16*w + c16;

    const float dt = dtp[0];
    const int nsteps = stepsp[0];
    const size_t T3 = (size_t)(nsteps + 1) * 3;
    const long blk = blockIdx.x;

    // ---- B-fragments of W_hh (this wave's 3 gate tiles), 3-way bf16 split ----
    // B[k][col]: col = lane&15 (unit), k = (lane>>4)*8 + j  (kappa*32 offset)
    short8 WB[3][2][3];   // [gate][kappa][part: hi/mid/lo]
    #pragma unroll
    for (int gate = 0; gate < 3; ++gate) {
        const float* row = Whh + (size_t)(gate*64 + unit) * 64;
        #pragma unroll
        for (int kk = 0; kk < 2; ++kk) {
            const float* p = row + 32*kk + 8*g;
            short8 bh_, bm_, bl_;
            #pragma unroll
            for (int j = 0; j < 8; ++j) {
                float x = p[j];
                unsigned hb = bf16r(x); float fh = bf16f(hb);
                float r1 = x - fh;
                unsigned mb = bf16r(r1); float fm = bf16f(mb);
                unsigned lb = bf16r(r1 - fm);
                bh_[j] = (short)hb; bm_[j] = (short)mb; bl_[j] = (short)lb;
            }
            WB[gate][kk][0] = bh_; WB[gate][kk][1] = bm_; WB[gate][kk][2] = bl_;
        }
    }
    // ---- head B-fragments (waves 0,1; cols >= 3 are zero) ----
    short8 HB[2][2];      // [kappa][part hi/mid]
    {
        short8 z8 = {0,0,0,0,0,0,0,0};
        HB[0][0]=z8; HB[0][1]=z8; HB[1][0]=z8; HB[1][1]=z8;
        if (w < 2 && c16 < 3) {
            #pragma unroll
            for (int kk = 0; kk < 2; ++kk) {
                const float* p = Whead + (size_t)c16*64 + 32*kk + 8*g;
                short8 bh_, bm_;
                #pragma unroll
                for (int j = 0; j < 8; ++j) {
                    float x = p[j];
                    unsigned hb = bf16r(x); float fh = bf16f(hb);
                    unsigned mb = bf16r(x - fh);
                    bh_[j] = (short)hb; bm_[j] = (short)mb;
                }
                HB[kk][0] = bh_; HB[kk][1] = bm_;
            }
        }
    }

    // ---- per-lane scalar weights / biases ----
    const float wir0 = Wih[(0*64+unit)*3+0], wir1 = Wih[(0*64+unit)*3+1], wir2 = Wih[(0*64+unit)*3+2];
    const float wiu0 = Wih[(1*64+unit)*3+0], wiu1 = Wih[(1*64+unit)*3+1], wiu2 = Wih[(1*64+unit)*3+2];
    const float win0 = Wih[(2*64+unit)*3+0], win1 = Wih[(2*64+unit)*3+1], win2 = Wih[(2*64+unit)*3+2];
    const float br   = bih[0*64+unit] + bhh[0*64+unit];
    const float bu   = bih[1*64+unit] + bhh[1*64+unit];
    const float bin_ = bih[2*64+unit];
    const float bhn  = bhh[2*64+unit];
    const float bhc  = (c16 < 3) ? bhead[c16] : 0.f;

    // ---- z init: wave w<2 owns M-tile mt=w; lanes c16<3 own component c16 ----
    float zreg[4] = {0.f,0.f,0.f,0.f};
    float* outg = out + ((size_t)(blk*MELEM + 4*g)) * T3 + c16;   // + (w*16+r)*T3 later
    if (w < 2 && c16 < 3) {
        #pragma unroll
        for (int r = 0; r < 4; ++r) {
            int e = w*16 + 4*g + r;
            float zv = z0[(size_t)(blk*MELEM + e)*3 + c16];
            zreg[r] = zv;
            zsh[e*4 + c16] = zv;
            outg[(size_t)(w*16 + r) * T3] = zv;
        }
    }

    // persistent A-fragments of h (h_0 = 0) and lane-local fp32 h
    short8 FA[2][2][3];   // [Mtile][kappa][part]
    {
        short8 z8 = {0,0,0,0,0,0,0,0};
        #pragma unroll
        for (int mt = 0; mt < 2; ++mt)
            #pragma unroll
            for (int kk = 0; kk < 2; ++kk) {
                FA[mt][kk][0]=z8; FA[mt][kk][1]=z8; FA[mt][kk][2]=z8;
            }
    }
    float hC[2][4] = {{0,0,0,0},{0,0,0,0}};

    __syncthreads();

    for (int t = 0; t < nsteps; ++t) {
        // ---- 1) gates GEMM: G = W_hh * h_t  (6-term split-3 bf16 ~= fp32) ----
        f32x4 acc[2][3];
        #pragma unroll
        for (int mt = 0; mt < 2; ++mt)
            #pragma unroll
            for (int gate = 0; gate < 3; ++gate) {
                f32x4 a = {0.f,0.f,0.f,0.f};
                #pragma unroll
                for (int kk = 0; kk < 2; ++kk) {
                    a = __builtin_amdgcn_mfma_f32_16x16x32_bf16(FA[mt][kk][0], WB[gate][kk][0], a, 0,0,0);
                    a = __builtin_amdgcn_mfma_f32_16x16x32_bf16(FA[mt][kk][1], WB[gate][kk][0], a, 0,0,0);
                    a = __builtin_amdgcn_mfma_f32_16x16x32_bf16(FA[mt][kk][0], WB[gate][kk][1], a, 0,0,0);
                    a = __builtin_amdgcn_mfma_f32_16x16x32_bf16(FA[mt][kk][2], WB[gate][kk][0], a, 0,0,0);
                    a = __builtin_amdgcn_mfma_f32_16x16x32_bf16(FA[mt][kk][0], WB[gate][kk][2], a, 0,0,0);
                    a = __builtin_amdgcn_mfma_f32_16x16x32_bf16(FA[mt][kk][1], WB[gate][kk][1], a, 0,0,0);
                }
                acc[mt][gate] = a;
            }

        // ---- 2,3) gate finish (C layout: row=4g+r, col=unit), h update, split+LDS ----
        #pragma unroll
        for (int mt = 0; mt < 2; ++mt) {
            #pragma unroll
            for (int r = 0; r < 4; ++r) {
                int e = mt*16 + 4*g + r;
                float z0v = zsh[e*4+0], z1v = zsh[e*4+1], z2v = zsh[e*4+2];
                float ar  = acc[mt][0][r] + br  + (wir0*z0v + wir1*z1v + wir2*z2v);
                float au  = acc[mt][1][r] + bu  + (wiu0*z0v + wiu1*z1v + wiu2*z2v);
                float anh = acc[mt][2][r] + bhn;
                float ain = bin_ + (win0*z0v + win1*z1v + win2*z2v);
                float rg = fast_sigmoid(ar);
                float ug = fast_sigmoid(au);
                float ng = fast_tanh(ain + rg*anh);
                float hn = ng + ug*(hC[mt][r] - ng);      // (1-u)n + u h
                hC[mt][r] = hn;
                unsigned hb = bf16r(hn); float fh = bf16f(hb);
                float r1 = hn - fh;
                unsigned mb = bf16r(r1); float fm = bf16f(mb);
                unsigned lb = bf16r(r1 - fm);
                int ad = e*HS + unit;
                hhi[ad] = (ushort)hb; hmi[ad] = (ushort)mb; hlo[ad] = (ushort)lb;
            }
        }
        __syncthreads();

        // ---- 5) rebuild A-fragments of h_{t+1}: A[row=c16][k=32kk+8g+j] ----
        #pragma unroll
        for (int mt = 0; mt < 2; ++mt)
            #pragma unroll
            for (int kk = 0; kk < 2; ++kk) {
                int ad = (mt*16 + c16)*HS + 32*kk + 8*g;
                FA[mt][kk][0] = *(const short8*)&hhi[ad];
                FA[mt][kk][1] = *(const short8*)&hmi[ad];
                FA[mt][kk][2] = *(const short8*)&hlo[ad];
            }

        // ---- 6) head GEMM on h_{t+1} (wave w<2 does M-tile w) + z update ----
        if (w < 2) {
            f32x4 a = {0.f,0.f,0.f,0.f};
            #pragma unroll
            for (int kk = 0; kk < 2; ++kk) {
                a = __builtin_amdgcn_mfma_f32_16x16x32_bf16(FA[w][kk][0], HB[kk][0], a, 0,0,0);
                a = __builtin_amdgcn_mfma_f32_16x16x32_bf16(FA[w][kk][1], HB[kk][0], a, 0,0,0);
                a = __builtin_amdgcn_mfma_f32_16x16x32_bf16(FA[w][kk][0], HB[kk][1], a, 0,0,0);
            }
            if (c16 < 3) {
                #pragma unroll
                for (int r = 0; r < 4; ++r) {
                    float zv = zreg[r] + dt*(a[r] + bhc);
                    zreg[r] = zv;
                    int e = w*16 + 4*g + r;
                    zsh[e*4 + c16] = zv;
                    outg[(size_t)(w*16 + r)*T3 + (size_t)(t+1)*3] = zv;
                }
            }
        }
        __syncthreads();
    }
}

extern "C" void kernel_launch(void* const* d_in, const int* in_sizes, int n_in,
                              void* d_out, int out_size, void* d_ws, size_t ws_size,
                              hipStream_t stream) {
    const float* z0    = (const float*)d_in[0];
    const float* dtp   = (const float*)d_in[1];
    const int*   steps = (const int*)  d_in[2];
    const float* Wih   = (const float*)d_in[3];
    const float* Whh   = (const float*)d_in[4];
    const float* bih   = (const float*)d_in[5];
    const float* bhh   = (const float*)d_in[6];
    const float* Whead = (const float*)d_in[7];
    const float* bhead = (const float*)d_in[8];
    float* out = (float*)d_out;

    const int B = in_sizes[0] / 3;          // 16384
    const int nblk = B / MELEM;             // 512 blocks x 256 threads

    hipLaunchKernelGGL(gru_mfma_kernel, dim3(nblk), dim3(256), 0, stream,
                       z0, dtp, steps, Wih, Whh, bih, bhh, Whead, bhead, out);
}

// Round 4
// 14117.763 us; speedup vs baseline: 2.0761x; 1.0067x over previous
//
#include <hip/hip_runtime.h>

typedef short short8 __attribute__((ext_vector_type(8)));
typedef float f32x4 __attribute__((ext_vector_type(4)));

#define LOG2E 1.44269504088896340736f
#define MELEM 32          // batch elems per block (2 M-tiles of 16)
#define HS 72             // u16 stride of h LDS rows (16B-aligned, bank-spread)
#define NT 32             // traj steps staged in LDS between flushes
#define TSTR (NT*3 + 1)   // 97: dword stride of traj staging rows (bank-spread)

__device__ __forceinline__ float fast_sigmoid(float x) {
    float t = __builtin_amdgcn_exp2f(-x * LOG2E);
    return __builtin_amdgcn_rcpf(1.f + t);
}
__device__ __forceinline__ float fast_tanh(float x) {
    float t = __builtin_amdgcn_exp2f(x * (2.f * LOG2E));
    return 1.f - 2.f * __builtin_amdgcn_rcpf(1.f + t);
}
__device__ __forceinline__ unsigned bf16r(float x) {   // RNE float->bf16 bits
    unsigned u = __builtin_bit_cast(unsigned, x);
    return (u + 0x7fffu + ((u >> 16) & 1u)) >> 16;
}
__device__ __forceinline__ float bf16f(unsigned b) {
    return __builtin_bit_cast(float, b << 16);
}

__global__ __launch_bounds__(256, 2)
void gru_mfma_kernel(const float* __restrict__ z0,
                     const float* __restrict__ dtp,
                     const int* __restrict__ stepsp,
                     const float* __restrict__ Wih,
                     const float* __restrict__ Whh,
                     const float* __restrict__ bih,
                     const float* __restrict__ bhh,
                     const float* __restrict__ Whead,
                     const float* __restrict__ bhead,
                     float* __restrict__ out)
{
    __shared__ __align__(16) ushort hhi[MELEM*HS];
    __shared__ __align__(16) ushort hmi[MELEM*HS];
    __shared__ __align__(16) ushort hlo[MELEM*HS];
    __shared__ float zsh[MELEM*4];
    __shared__ float tbuf[MELEM][TSTR];   // staged traj: [elem][(t%NT)*3 + comp]

    const int tid = threadIdx.x;
    const int w   = tid >> 6;       // wave 0..3 -> unit range [16w,16w+16)
    const int l   = tid & 63;
    const int c16 = l & 15;
    const int g   = l >> 4;         // 0..3
    const int unit = 16*w + c16;

    const float dt = dtp[0];
    const int nsteps = stepsp[0];
    const size_t T3 = (size_t)(nsteps + 1) * 3;
    const long blk = blockIdx.x;

    // ---- B-fragments of W_hh (this wave's 3 gate tiles), 3-way bf16 split ----
    // B[k][col]: col = lane&15 (unit), k = (lane>>4)*8 + j  (kappa*32 offset)
    short8 WB[3][2][3];   // [gate][kappa][part: hi/mid/lo]
    #pragma unroll
    for (int gate = 0; gate < 3; ++gate) {
        const float* row = Whh + (size_t)(gate*64 + unit) * 64;
        #pragma unroll
        for (int kk = 0; kk < 2; ++kk) {
            const float* p = row + 32*kk + 8*g;
            short8 bh_, bm_, bl_;
            #pragma unroll
            for (int j = 0; j < 8; ++j) {
                float x = p[j];
                unsigned hb = bf16r(x); float fh = bf16f(hb);
                float r1 = x - fh;
                unsigned mb = bf16r(r1); float fm = bf16f(mb);
                unsigned lb = bf16r(r1 - fm);
                bh_[j] = (short)hb; bm_[j] = (short)mb; bl_[j] = (short)lb;
            }
            WB[gate][kk][0] = bh_; WB[gate][kk][1] = bm_; WB[gate][kk][2] = bl_;
        }
    }
    // ---- head B-fragments (waves 0,1; cols >= 3 are zero) ----
    short8 HB[2][2];      // [kappa][part hi/mid]
    {
        short8 z8 = {0,0,0,0,0,0,0,0};
        HB[0][0]=z8; HB[0][1]=z8; HB[1][0]=z8; HB[1][1]=z8;
        if (w < 2 && c16 < 3) {
            #pragma unroll
            for (int kk = 0; kk < 2; ++kk) {
                const float* p = Whead + (size_t)c16*64 + 32*kk + 8*g;
                short8 bh_, bm_;
                #pragma unroll
                for (int j = 0; j < 8; ++j) {
                    float x = p[j];
                    unsigned hb = bf16r(x); float fh = bf16f(hb);
                    unsigned mb = bf16r(x - fh);
                    bh_[j] = (short)hb; bm_[j] = (short)mb;
                }
                HB[kk][0] = bh_; HB[kk][1] = bm_;
            }
        }
    }

    // ---- per-lane scalar weights / biases ----
    const float wir0 = Wih[(0*64+unit)*3+0], wir1 = Wih[(0*64+unit)*3+1], wir2 = Wih[(0*64+unit)*3+2];
    const float wiu0 = Wih[(1*64+unit)*3+0], wiu1 = Wih[(1*64+unit)*3+1], wiu2 = Wih[(1*64+unit)*3+2];
    const float win0 = Wih[(2*64+unit)*3+0], win1 = Wih[(2*64+unit)*3+1], win2 = Wih[(2*64+unit)*3+2];
    const float br   = bih[0*64+unit] + bhh[0*64+unit];
    const float bu   = bih[1*64+unit] + bhh[1*64+unit];
    const float bin_ = bih[2*64+unit];
    const float bhn  = bhh[2*64+unit];
    const float bhc  = (c16 < 3) ? bhead[c16] : 0.f;

    // ---- z init: wave w<2 owns M-tile mt=w; lanes c16<3 own component c16 ----
    float zreg[4] = {0.f,0.f,0.f,0.f};
    if (w < 2 && c16 < 3) {
        #pragma unroll
        for (int r = 0; r < 4; ++r) {
            int e = w*16 + 4*g + r;
            float zv = z0[(size_t)(blk*MELEM + e)*3 + c16];
            zreg[r] = zv;
            zsh[e*4 + c16] = zv;
            // t=0 row (once; scattered but negligible)
            out[(size_t)(blk*MELEM + e)*T3 + c16] = zv;
        }
    }

    // persistent A-fragments of h (h_0 = 0) and lane-local fp32 h
    short8 FA[2][2][3];   // [Mtile][kappa][part]
    {
        short8 z8 = {0,0,0,0,0,0,0,0};
        #pragma unroll
        for (int mt = 0; mt < 2; ++mt)
            #pragma unroll
            for (int kk = 0; kk < 2; ++kk) {
                FA[mt][kk][0]=z8; FA[mt][kk][1]=z8; FA[mt][kk][2]=z8;
            }
    }
    float hC[2][4] = {{0,0,0,0},{0,0,0,0}};

    __syncthreads();

    for (int t = 0; t < nsteps; ++t) {
        // ---- 1) gates GEMM: G = W_hh * h_t  (6-term split-3 bf16 ~= fp32) ----
        f32x4 acc[2][3];
        #pragma unroll
        for (int mt = 0; mt < 2; ++mt)
            #pragma unroll
            for (int gate = 0; gate < 3; ++gate) {
                f32x4 a = {0.f,0.f,0.f,0.f};
                #pragma unroll
                for (int kk = 0; kk < 2; ++kk) {
                    a = __builtin_amdgcn_mfma_f32_16x16x32_bf16(FA[mt][kk][0], WB[gate][kk][0], a, 0,0,0);
                    a = __builtin_amdgcn_mfma_f32_16x16x32_bf16(FA[mt][kk][1], WB[gate][kk][0], a, 0,0,0);
                    a = __builtin_amdgcn_mfma_f32_16x16x32_bf16(FA[mt][kk][0], WB[gate][kk][1], a, 0,0,0);
                    a = __builtin_amdgcn_mfma_f32_16x16x32_bf16(FA[mt][kk][2], WB[gate][kk][0], a, 0,0,0);
                    a = __builtin_amdgcn_mfma_f32_16x16x32_bf16(FA[mt][kk][0], WB[gate][kk][2], a, 0,0,0);
                    a = __builtin_amdgcn_mfma_f32_16x16x32_bf16(FA[mt][kk][1], WB[gate][kk][1], a, 0,0,0);
                }
                acc[mt][gate] = a;
            }

        // ---- 2,3) gate finish (C layout: row=4g+r, col=unit), h update, split+LDS ----
        #pragma unroll
        for (int mt = 0; mt < 2; ++mt) {
            #pragma unroll
            for (int r = 0; r < 4; ++r) {
                int e = mt*16 + 4*g + r;
                float z0v = zsh[e*4+0], z1v = zsh[e*4+1], z2v = zsh[e*4+2];
                float ar  = acc[mt][0][r] + br  + (wir0*z0v + wir1*z1v + wir2*z2v);
                float au  = acc[mt][1][r] + bu  + (wiu0*z0v + wiu1*z1v + wiu2*z2v);
                float anh = acc[mt][2][r] + bhn;
                float ain = bin_ + (win0*z0v + win1*z1v + win2*z2v);
                float rg = fast_sigmoid(ar);
                float ug = fast_sigmoid(au);
                float ng = fast_tanh(ain + rg*anh);
                float hn = ng + ug*(hC[mt][r] - ng);      // (1-u)n + u h
                hC[mt][r] = hn;
                unsigned hb = bf16r(hn); float fh = bf16f(hb);
                float r1 = hn - fh;
                unsigned mb = bf16r(r1); float fm = bf16f(mb);
                unsigned lb = bf16r(r1 - fm);
                int ad = e*HS + unit;
                hhi[ad] = (ushort)hb; hmi[ad] = (ushort)mb; hlo[ad] = (ushort)lb;
            }
        }
        __syncthreads();

        // ---- 5) rebuild A-fragments of h_{t+1}: A[row=c16][k=32kk+8g+j] ----
        #pragma unroll
        for (int mt = 0; mt < 2; ++mt)
            #pragma unroll
            for (int kk = 0; kk < 2; ++kk) {
                int ad = (mt*16 + c16)*HS + 32*kk + 8*g;
                FA[mt][kk][0] = *(const short8*)&hhi[ad];
                FA[mt][kk][1] = *(const short8*)&hmi[ad];
                FA[mt][kk][2] = *(const short8*)&hlo[ad];
            }

        // ---- 6) head GEMM on h_{t+1} (wave w<2 does M-tile w) + z update ----
        if (w < 2) {
            f32x4 a = {0.f,0.f,0.f,0.f};
            #pragma unroll
            for (int kk = 0; kk < 2; ++kk) {
                a = __builtin_amdgcn_mfma_f32_16x16x32_bf16(FA[w][kk][0], HB[kk][0], a, 0,0,0);
                a = __builtin_amdgcn_mfma_f32_16x16x32_bf16(FA[w][kk][1], HB[kk][0], a, 0,0,0);
                a = __builtin_amdgcn_mfma_f32_16x16x32_bf16(FA[w][kk][0], HB[kk][1], a, 0,0,0);
            }
            if (c16 < 3) {
                const int tt = t & (NT-1);
                #pragma unroll
                for (int r = 0; r < 4; ++r) {
                    float zv = zreg[r] + dt*(a[r] + bhc);
                    zreg[r] = zv;
                    int e = w*16 + 4*g + r;
                    zsh[e*4 + c16] = zv;
                    tbuf[e][tt*3 + c16] = zv;     // stage in LDS
                }
            }
        }
        __syncthreads();

        // ---- 7) coalesced flush of staged traj every NT steps ----
        if ((t & (NT-1)) == (NT-1)) {
            const int base_t = t - (NT-1);
            // 32 elems x NT*3=96 dwords = 3072 dwords; 12 per thread, dense lines
            #pragma unroll
            for (int k = 0; k < (MELEM*NT*3)/256; ++k) {
                int idx = tid + k*256;
                int e   = idx / (NT*3);
                int off = idx - e*(NT*3);
                out[(size_t)(blk*MELEM + e)*T3 + (size_t)(base_t+1)*3 + off] =
                    tbuf[e][off];
            }
            // no extra barrier needed: tbuf is next written only after the
            // mid-step __syncthreads of step t+1, by which time every thread
            // has consumed its LDS reads for this flush.
        }
    }

    // tail flush for nsteps not a multiple of NT (not hit for 2048)
    const int rem = nsteps & (NT-1);
    if (rem) {
        const int base_t = nsteps - rem;
        const int rem3 = rem*3;
        for (int idx = tid; idx < MELEM*rem3; idx += 256) {
            int e = idx / rem3;
            int off = idx - e*rem3;
            out[(size_t)(blk*MELEM + e)*T3 + (size_t)(base_t+1)*3 + off] =
                tbuf[e][off];
        }
    }
}

extern "C" void kernel_launch(void* const* d_in, const int* in_sizes, int n_in,
                              void* d_out, int out_size, void* d_ws, size_t ws_size,
                              hipStream_t stream) {
    const float* z0    = (const float*)d_in[0];
    const float* dtp   = (const float*)d_in[1];
    const int*   steps = (const int*)  d_in[2];
    const float* Wih   = (const float*)d_in[3];
    const float* Whh   = (const float*)d_in[4];
    const float* bih   = (const float*)d_in[5];
    const float* bhh   = (const float*)d_in[6];
    const float* Whead = (const float*)d_in[7];
    const float* bhead = (const float*)d_in[8];
    float* out = (float*)d_out;

    const int B = in_sizes[0] / 3;          // 16384
    const int nblk = B / MELEM;             // 512 blocks x 256 threads

    hipLaunchKernelGGL(gru_mfma_kernel, dim3(nblk), dim3(256), 0, stream,
                       z0, dtp, steps, Wih, Whh, bih, bhh, Whead, bhead, out);
}

// Round 5
// 6432.999 us; speedup vs baseline: 4.5562x; 2.1946x over previous
//
#include <hip/hip_runtime.h>

typedef short short8 __attribute__((ext_vector_type(8)));
typedef float f32x4 __attribute__((ext_vector_type(4)));

#define LOG2E 1.44269504088896340736f
#define MELEM 32          // batch elems per block (2 M-tiles of 16)
#define HS 72             // u16 stride of h LDS rows (16B-aligned, bank-spread)
#define NT 32             // traj steps staged in LDS between flushes
#define TSTR (NT*3 + 1)   // 97: dword stride of traj staging rows (bank-spread)

__device__ __forceinline__ float fast_sigmoid(float x) {
    float t = __builtin_amdgcn_exp2f(-x * LOG2E);
    return __builtin_amdgcn_rcpf(1.f + t);
}
__device__ __forceinline__ float fast_tanh(float x) {
    float t = __builtin_amdgcn_exp2f(x * (2.f * LOG2E));
    return 1.f - 2.f * __builtin_amdgcn_rcpf(1.f + t);
}
__device__ __forceinline__ unsigned bf16r(float x) {   // RNE float->bf16 bits
    unsigned u = __builtin_bit_cast(unsigned, x);
    return (u + 0x7fffu + ((u >> 16) & 1u)) >> 16;
}
__device__ __forceinline__ float bf16f(unsigned b) {
    return __builtin_bit_cast(float, b << 16);
}

__global__ __launch_bounds__(256, 2)
void gru_mfma_kernel(const float* __restrict__ z0,
                     const float* __restrict__ dtp,
                     const int* __restrict__ stepsp,
                     const float* __restrict__ Wih,
                     const float* __restrict__ Whh,
                     const float* __restrict__ bih,
                     const float* __restrict__ bhh,
                     const float* __restrict__ Whead,
                     const float* __restrict__ bhead,
                     float* __restrict__ out)
{
    __shared__ __align__(16) ushort hhi[MELEM*HS];
    __shared__ __align__(16) ushort hmi[MELEM*HS];
    __shared__ __align__(16) ushort hlo[MELEM*HS];
    __shared__ float zsh[MELEM*4];
    __shared__ float tbuf[MELEM][TSTR];   // staged traj: [elem][(t%NT)*3 + comp]

    const int tid = threadIdx.x;
    const int w   = tid >> 6;       // wave 0..3 -> unit range [16w,16w+16)
    const int l   = tid & 63;
    const int c16 = l & 15;
    const int g   = l >> 4;         // 0..3
    const int unit = 16*w + c16;

    const float dt = dtp[0];
    const int nsteps = stepsp[0];
    const size_t T3 = (size_t)(nsteps + 1) * 3;
    const long blk = blockIdx.x;

    // ---- B-fragments of W_hh (this wave's 3 gate tiles), 3-way bf16 split ----
    // B[k][col]: col = lane&15 (unit), k = (lane>>4)*8 + j  (kappa*32 offset)
    short8 WB[3][2][3];   // [gate][kappa][part: hi/mid/lo]
    #pragma unroll
    for (int gate = 0; gate < 3; ++gate) {
        const float* row = Whh + (size_t)(gate*64 + unit) * 64;
        #pragma unroll
        for (int kk = 0; kk < 2; ++kk) {
            const float* p = row + 32*kk + 8*g;
            short8 bh_, bm_, bl_;
            #pragma unroll
            for (int j = 0; j < 8; ++j) {
                float x = p[j];
                unsigned hb = bf16r(x); float fh = bf16f(hb);
                float r1 = x - fh;
                unsigned mb = bf16r(r1); float fm = bf16f(mb);
                unsigned lb = bf16r(r1 - fm);
                bh_[j] = (short)hb; bm_[j] = (short)mb; bl_[j] = (short)lb;
            }
            WB[gate][kk][0] = bh_; WB[gate][kk][1] = bm_; WB[gate][kk][2] = bl_;
        }
    }
    // ---- head B-fragments (waves 0,1; cols >= 3 are zero) ----
    short8 HB[2][2];      // [kappa][part hi/mid]
    {
        short8 z8 = {0,0,0,0,0,0,0,0};
        HB[0][0]=z8; HB[0][1]=z8; HB[1][0]=z8; HB[1][1]=z8;
        if (w < 2 && c16 < 3) {
            #pragma unroll
            for (int kk = 0; kk < 2; ++kk) {
                const float* p = Whead + (size_t)c16*64 + 32*kk + 8*g;
                short8 bh_, bm_;
                #pragma unroll
                for (int j = 0; j < 8; ++j) {
                    float x = p[j];
                    unsigned hb = bf16r(x); float fh = bf16f(hb);
                    unsigned mb = bf16r(x - fh);
                    bh_[j] = (short)hb; bm_[j] = (short)mb;
                }
                HB[kk][0] = bh_; HB[kk][1] = bm_;
            }
        }
    }

    // ---- per-lane scalar weights / biases ----
    const float wir0 = Wih[(0*64+unit)*3+0], wir1 = Wih[(0*64+unit)*3+1], wir2 = Wih[(0*64+unit)*3+2];
    const float wiu0 = Wih[(1*64+unit)*3+0], wiu1 = Wih[(1*64+unit)*3+1], wiu2 = Wih[(1*64+unit)*3+2];
    const float win0 = Wih[(2*64+unit)*3+0], win1 = Wih[(2*64+unit)*3+1], win2 = Wih[(2*64+unit)*3+2];
    const float br   = bih[0*64+unit] + bhh[0*64+unit];
    const float bu   = bih[1*64+unit] + bhh[1*64+unit];
    const float bin_ = bih[2*64+unit];
    const float bhn  = bhh[2*64+unit];
    const float bhc  = (c16 < 3) ? bhead[c16] : 0.f;

    // ---- z init: wave w<2 owns M-tile mt=w; lanes c16<3 own component c16 ----
    float zreg[4] = {0.f,0.f,0.f,0.f};
    if (w < 2 && c16 < 3) {
        #pragma unroll
        for (int r = 0; r < 4; ++r) {
            int e = w*16 + 4*g + r;
            float zv = z0[(size_t)(blk*MELEM + e)*3 + c16];
            zreg[r] = zv;
            zsh[e*4 + c16] = zv;
            // t=0 row (once; scattered but negligible)
            out[(size_t)(blk*MELEM + e)*T3 + c16] = zv;
        }
    }

    // persistent A-fragments of h (h_0 = 0) and lane-local fp32 h
    short8 FA[2][2][3];   // [Mtile][kappa][part] -- ALL indices compile-time!
    {
        short8 z8 = {0,0,0,0,0,0,0,0};
        #pragma unroll
        for (int mt = 0; mt < 2; ++mt)
            #pragma unroll
            for (int kk = 0; kk < 2; ++kk) {
                FA[mt][kk][0]=z8; FA[mt][kk][1]=z8; FA[mt][kk][2]=z8;
            }
    }
    float hC[2][4] = {{0,0,0,0},{0,0,0,0}};

    __syncthreads();

    for (int t = 0; t < nsteps; ++t) {
        // ---- 1) gates GEMM: G = W_hh * h_t  (6-term split-3 bf16 ~= fp32) ----
        f32x4 acc[2][3];
        #pragma unroll
        for (int mt = 0; mt < 2; ++mt)
            #pragma unroll
            for (int gate = 0; gate < 3; ++gate) {
                f32x4 a = {0.f,0.f,0.f,0.f};
                #pragma unroll
                for (int kk = 0; kk < 2; ++kk) {
                    a = __builtin_amdgcn_mfma_f32_16x16x32_bf16(FA[mt][kk][0], WB[gate][kk][0], a, 0,0,0);
                    a = __builtin_amdgcn_mfma_f32_16x16x32_bf16(FA[mt][kk][1], WB[gate][kk][0], a, 0,0,0);
                    a = __builtin_amdgcn_mfma_f32_16x16x32_bf16(FA[mt][kk][0], WB[gate][kk][1], a, 0,0,0);
                    a = __builtin_amdgcn_mfma_f32_16x16x32_bf16(FA[mt][kk][2], WB[gate][kk][0], a, 0,0,0);
                    a = __builtin_amdgcn_mfma_f32_16x16x32_bf16(FA[mt][kk][0], WB[gate][kk][2], a, 0,0,0);
                    a = __builtin_amdgcn_mfma_f32_16x16x32_bf16(FA[mt][kk][1], WB[gate][kk][1], a, 0,0,0);
                }
                acc[mt][gate] = a;
            }

        // ---- 2,3) gate finish (C layout: row=4g+r, col=unit), h update, split+LDS ----
        #pragma unroll
        for (int mt = 0; mt < 2; ++mt) {
            #pragma unroll
            for (int r = 0; r < 4; ++r) {
                int e = mt*16 + 4*g + r;
                float z0v = zsh[e*4+0], z1v = zsh[e*4+1], z2v = zsh[e*4+2];
                float ar  = acc[mt][0][r] + br  + (wir0*z0v + wir1*z1v + wir2*z2v);
                float au  = acc[mt][1][r] + bu  + (wiu0*z0v + wiu1*z1v + wiu2*z2v);
                float anh = acc[mt][2][r] + bhn;
                float ain = bin_ + (win0*z0v + win1*z1v + win2*z2v);
                float rg = fast_sigmoid(ar);
                float ug = fast_sigmoid(au);
                float ng = fast_tanh(ain + rg*anh);
                float hn = ng + ug*(hC[mt][r] - ng);      // (1-u)n + u h
                hC[mt][r] = hn;
                unsigned hb = bf16r(hn); float fh = bf16f(hb);
                float r1 = hn - fh;
                unsigned mb = bf16r(r1); float fm = bf16f(mb);
                unsigned lb = bf16r(r1 - fm);
                int ad = e*HS + unit;
                hhi[ad] = (ushort)hb; hmi[ad] = (ushort)mb; hlo[ad] = (ushort)lb;
            }
        }
        __syncthreads();

        // ---- 5) rebuild A-fragments of h_{t+1}: A[row=c16][k=32kk+8g+j] ----
        #pragma unroll
        for (int mt = 0; mt < 2; ++mt)
            #pragma unroll
            for (int kk = 0; kk < 2; ++kk) {
                int ad = (mt*16 + c16)*HS + 32*kk + 8*g;
                FA[mt][kk][0] = *(const short8*)&hhi[ad];
                FA[mt][kk][1] = *(const short8*)&hmi[ad];
                FA[mt][kk][2] = *(const short8*)&hlo[ad];
            }

        // ---- 6) head GEMM on h_{t+1}; STATIC FA index per wave (no scratch) ----
        #define HEAD_GEMM(MT)                                                                   \
            do {                                                                                \
                _Pragma("unroll")                                                               \
                for (int kk = 0; kk < 2; ++kk) {                                                \
                    a = __builtin_amdgcn_mfma_f32_16x16x32_bf16(FA[MT][kk][0], HB[kk][0], a, 0,0,0); \
                    a = __builtin_amdgcn_mfma_f32_16x16x32_bf16(FA[MT][kk][1], HB[kk][0], a, 0,0,0); \
                    a = __builtin_amdgcn_mfma_f32_16x16x32_bf16(FA[MT][kk][0], HB[kk][1], a, 0,0,0); \
                }                                                                               \
            } while (0)

        if (w < 2) {
            f32x4 a = {0.f,0.f,0.f,0.f};
            if (w == 0) { HEAD_GEMM(0); } else { HEAD_GEMM(1); }
            if (c16 < 3) {
                const int tt = t & (NT-1);
                #pragma unroll
                for (int r = 0; r < 4; ++r) {
                    float zv = zreg[r] + dt*(a[r] + bhc);
                    zreg[r] = zv;
                    int e = w*16 + 4*g + r;
                    zsh[e*4 + c16] = zv;
                    tbuf[e][tt*3 + c16] = zv;     // stage in LDS
                }
            }
        }
        __syncthreads();

        // ---- 7) coalesced flush of staged traj every NT steps ----
        if ((t & (NT-1)) == (NT-1)) {
            const int base_t = t - (NT-1);
            // 32 elems x NT*3=96 dwords = 3072 dwords; 12 per thread, dense lines
            #pragma unroll
            for (int k = 0; k < (MELEM*NT*3)/256; ++k) {
                int idx = tid + k*256;
                int e   = idx / (NT*3);
                int off = idx - e*(NT*3);
                out[(size_t)(blk*MELEM + e)*T3 + (size_t)(base_t+1)*3 + off] =
                    tbuf[e][off];
            }
            // no extra barrier needed: tbuf is next written only after the
            // mid-step __syncthreads of step t+1, by which time every thread
            // has consumed its LDS reads for this flush.
        }
    }

    // tail flush for nsteps not a multiple of NT (not hit for 2048)
    const int rem = nsteps & (NT-1);
    if (rem) {
        const int base_t = nsteps - rem;
        const int rem3 = rem*3;
        for (int idx = tid; idx < MELEM*rem3; idx += 256) {
            int e = idx / rem3;
            int off = idx - e*rem3;
            out[(size_t)(blk*MELEM + e)*T3 + (size_t)(base_t+1)*3 + off] =
                tbuf[e][off];
        }
    }
}

extern "C" void kernel_launch(void* const* d_in, const int* in_sizes, int n_in,
                              void* d_out, int out_size, void* d_ws, size_t ws_size,
                              hipStream_t stream) {
    const float* z0    = (const float*)d_in[0];
    const float* dtp   = (const float*)d_in[1];
    const int*   steps = (const int*)  d_in[2];
    const float* Wih   = (const float*)d_in[3];
    const float* Whh   = (const float*)d_in[4];
    const float* bih   = (const float*)d_in[5];
    const float* bhh   = (const float*)d_in[6];
    const float* Whead = (const float*)d_in[7];
    const float* bhead = (const float*)d_in[8];
    float* out = (float*)d_out;

    const int B = in_sizes[0] / 3;          // 16384
    const int nblk = B / MELEM;             // 512 blocks x 256 threads

    hipLaunchKernelGGL(gru_mfma_kernel, dim3(nblk), dim3(256), 0, stream,
                       z0, dtp, steps, Wih, Whh, bih, bhh, Whead, bhead, out);
}

// Round 6
// 6150.225 us; speedup vs baseline: 4.7657x; 1.0460x over previous
//
#include <hip/hip_runtime.h>

typedef short short8 __attribute__((ext_vector_type(8)));
typedef float f32x4 __attribute__((ext_vector_type(4)));

#define LOG2E 1.44269504088896340736f
#define MELEM 32          // batch elems per block (2 M-tiles of 16)
#define HS 72             // u16 stride of h LDS rows (16B-aligned, bank-spread)

__device__ __forceinline__ float fast_sigmoid(float x) {
    float t = __builtin_amdgcn_exp2f(-x * LOG2E);
    return __builtin_amdgcn_rcpf(1.f + t);
}
__device__ __forceinline__ float fast_tanh(float x) {
    float t = __builtin_amdgcn_exp2f(x * (2.f * LOG2E));
    return 1.f - 2.f * __builtin_amdgcn_rcpf(1.f + t);
}
__device__ __forceinline__ unsigned bf16r(float x) {   // RNE float->bf16 bits
    unsigned u = __builtin_bit_cast(unsigned, x);
    return (u + 0x7fffu + ((u >> 16) & 1u)) >> 16;
}
__device__ __forceinline__ float bf16f(unsigned b) {
    return __builtin_bit_cast(float, b << 16);
}

__global__ __launch_bounds__(256, 2)
void gru_mfma_kernel(const float* __restrict__ z0,
                     const float* __restrict__ dtp,
                     const int* __restrict__ stepsp,
                     const float* __restrict__ Wih,
                     const float* __restrict__ Whh,
                     const float* __restrict__ bih,
                     const float* __restrict__ bhh,
                     const float* __restrict__ Whead,
                     const float* __restrict__ bhead,
                     float* __restrict__ out)
{
    // double-buffered 3-part split of h: [pingpong][part][elem*HS + unit]
    __shared__ __align__(16) ushort hbuf[2][3][MELEM*HS];

    const int tid = threadIdx.x;
    const int w   = tid >> 6;       // wave 0..3 -> unit range [16w,16w+16)
    const int l   = tid & 63;
    const int c16 = l & 15;
    const int g   = l >> 4;         // 0..3
    const int unit = 16*w + c16;

    const float dt = dtp[0];
    const int nsteps = stepsp[0];
    const size_t T3 = (size_t)(nsteps + 1) * 3;
    const long blk = blockIdx.x;

    // ---- B-fragments of W_hh (this wave's 3 gate tiles), 3-way bf16 split ----
    short8 WB[3][2][3];   // [gate][kappa][part: hi/mid/lo]
    #pragma unroll
    for (int gate = 0; gate < 3; ++gate) {
        const float* row = Whh + (size_t)(gate*64 + unit) * 64;
        #pragma unroll
        for (int kk = 0; kk < 2; ++kk) {
            const float* p = row + 32*kk + 8*g;
            short8 bh_, bm_, bl_;
            #pragma unroll
            for (int j = 0; j < 8; ++j) {
                float x = p[j];
                unsigned hb = bf16r(x); float fh = bf16f(hb);
                float r1 = x - fh;
                unsigned mb = bf16r(r1); float fm = bf16f(mb);
                unsigned lb = bf16r(r1 - fm);
                bh_[j] = (short)hb; bm_[j] = (short)mb; bl_[j] = (short)lb;
            }
            WB[gate][kk][0] = bh_; WB[gate][kk][1] = bm_; WB[gate][kk][2] = bl_;
        }
    }
    // ---- head B-fragments: ALL waves (redundant head GEMM kills z-exchange) ----
    short8 HB[2][2];      // [kappa][part hi/mid]; cols >= 3 zero
    {
        short8 z8 = {0,0,0,0,0,0,0,0};
        HB[0][0]=z8; HB[0][1]=z8; HB[1][0]=z8; HB[1][1]=z8;
        if (c16 < 3) {
            #pragma unroll
            for (int kk = 0; kk < 2; ++kk) {
                const float* p = Whead + (size_t)c16*64 + 32*kk + 8*g;
                short8 bh_, bm_;
                #pragma unroll
                for (int j = 0; j < 8; ++j) {
                    float x = p[j];
                    unsigned hb = bf16r(x); float fh = bf16f(hb);
                    unsigned mb = bf16r(x - fh);
                    bh_[j] = (short)hb; bm_[j] = (short)mb;
                }
                HB[kk][0] = bh_; HB[kk][1] = bm_;
            }
        }
    }

    // ---- per-lane scalar weights / biases ----
    const float wir0 = Wih[(0*64+unit)*3+0], wir1 = Wih[(0*64+unit)*3+1], wir2 = Wih[(0*64+unit)*3+2];
    const float wiu0 = Wih[(1*64+unit)*3+0], wiu1 = Wih[(1*64+unit)*3+1], wiu2 = Wih[(1*64+unit)*3+2];
    const float win0 = Wih[(2*64+unit)*3+0], win1 = Wih[(2*64+unit)*3+1], win2 = Wih[(2*64+unit)*3+2];
    const float br   = bih[0*64+unit] + bhh[0*64+unit];
    const float bu   = bih[1*64+unit] + bhh[1*64+unit];
    const float bin_ = bih[2*64+unit];
    const float bhn  = bhh[2*64+unit];
    const float bh0 = bhead[0], bh1 = bhead[1], bh2 = bhead[2];

    // ---- z replicated in registers on every lane (all indices static) ----
    float zreg[2][4][3];
    #pragma unroll
    for (int mt = 0; mt < 2; ++mt)
        #pragma unroll
        for (int r = 0; r < 4; ++r)
            #pragma unroll
            for (int c = 0; c < 3; ++c)
                zreg[mt][r][c] = z0[(size_t)(blk*MELEM + mt*16 + 4*g + r)*3 + c];

    // traj row 0 (designated lanes, static zreg indices via predication)
    #pragma unroll
    for (int mt = 0; mt < 2; ++mt)
        #pragma unroll
        for (int c = 0; c < 3; ++c)
            if (w == mt && c16 == c) {
                #pragma unroll
                for (int r = 0; r < 4; ++r)
                    out[(size_t)(blk*MELEM + mt*16 + 4*g + r)*T3 + c] = zreg[mt][r][c];
            }

    // ---- zero h buffer 0 (h_0 = 0) ----
    {
        uint* hz = (uint*)&hbuf[0][0][0];
        for (int idx = tid; idx < 3*MELEM*HS/2; idx += 256) hz[idx] = 0u;
    }

    float hC[2][4] = {{0,0,0,0},{0,0,0,0}};

    __syncthreads();

    for (int t = 0; t < nsteps; ++t) {
        const int p = t & 1;
        // ---- 1) A-fragments of h(t) from buf[p] ----
        short8 FA[2][2][3];   // [Mtile][kappa][part] (all static indices)
        #pragma unroll
        for (int mt = 0; mt < 2; ++mt)
            #pragma unroll
            for (int kk = 0; kk < 2; ++kk) {
                int ad = (mt*16 + c16)*HS + 32*kk + 8*g;
                FA[mt][kk][0] = *(const short8*)&hbuf[p][0][ad];
                FA[mt][kk][1] = *(const short8*)&hbuf[p][1][ad];
                FA[mt][kk][2] = *(const short8*)&hbuf[p][2][ad];
            }

        // ---- 2) head GEMM over h(t): f = Whead h(t) + bh  (every wave) ----
        f32x4 hacc[2];
        #pragma unroll
        for (int mt = 0; mt < 2; ++mt) {
            f32x4 a = {0.f,0.f,0.f,0.f};
            #pragma unroll
            for (int kk = 0; kk < 2; ++kk) {
                a = __builtin_amdgcn_mfma_f32_16x16x32_bf16(FA[mt][kk][0], HB[kk][0], a, 0,0,0);
                a = __builtin_amdgcn_mfma_f32_16x16x32_bf16(FA[mt][kk][1], HB[kk][0], a, 0,0,0);
                a = __builtin_amdgcn_mfma_f32_16x16x32_bf16(FA[mt][kk][0], HB[kk][1], a, 0,0,0);
            }
            hacc[mt] = a;
        }

        // ---- 3) z(t) = z(t-1) + dt*f (t>0); broadcast via intra-wave shfl;
        //         store traj row t ----
        if (t) {
            #pragma unroll
            for (int mt = 0; mt < 2; ++mt)
                #pragma unroll
                for (int r = 0; r < 4; ++r)
                    #pragma unroll
                    for (int c = 0; c < 3; ++c) {
                        float f = __shfl(hacc[mt][r], (l & 48) + c);
                        float bhv = (c == 0) ? bh0 : (c == 1) ? bh1 : bh2;
                        zreg[mt][r][c] += dt * (f + bhv);
                    }
            #pragma unroll
            for (int mt = 0; mt < 2; ++mt)
                #pragma unroll
                for (int c = 0; c < 3; ++c)
                    if (w == mt && c16 == c) {
                        #pragma unroll
                        for (int r = 0; r < 4; ++r)
                            out[(size_t)(blk*MELEM + mt*16 + 4*g + r)*T3
                                + (size_t)t*3 + c] = zreg[mt][r][c];
                    }
        }

        // ---- 4) gates GEMM: G = W_hh * h(t)  (6-term split-3 bf16 ~= fp32) ----
        f32x4 acc[2][3];
        #pragma unroll
        for (int mt = 0; mt < 2; ++mt)
            #pragma unroll
            for (int gate = 0; gate < 3; ++gate) {
                f32x4 a = {0.f,0.f,0.f,0.f};
                #pragma unroll
                for (int kk = 0; kk < 2; ++kk) {
                    a = __builtin_amdgcn_mfma_f32_16x16x32_bf16(FA[mt][kk][0], WB[gate][kk][0], a, 0,0,0);
                    a = __builtin_amdgcn_mfma_f32_16x16x32_bf16(FA[mt][kk][1], WB[gate][kk][0], a, 0,0,0);
                    a = __builtin_amdgcn_mfma_f32_16x16x32_bf16(FA[mt][kk][0], WB[gate][kk][1], a, 0,0,0);
                    a = __builtin_amdgcn_mfma_f32_16x16x32_bf16(FA[mt][kk][2], WB[gate][kk][0], a, 0,0,0);
                    a = __builtin_amdgcn_mfma_f32_16x16x32_bf16(FA[mt][kk][0], WB[gate][kk][2], a, 0,0,0);
                    a = __builtin_amdgcn_mfma_f32_16x16x32_bf16(FA[mt][kk][1], WB[gate][kk][1], a, 0,0,0);
                }
                acc[mt][gate] = a;
            }

        // ---- 5) gate finish (z from regs!), h update, 3-way split -> buf[p^1] ----
        #pragma unroll
        for (int mt = 0; mt < 2; ++mt) {
            #pragma unroll
            for (int r = 0; r < 4; ++r) {
                int e = mt*16 + 4*g + r;
                float z0v = zreg[mt][r][0], z1v = zreg[mt][r][1], z2v = zreg[mt][r][2];
                float ar  = acc[mt][0][r] + br  + (wir0*z0v + wir1*z1v + wir2*z2v);
                float au  = acc[mt][1][r] + bu  + (wiu0*z0v + wiu1*z1v + wiu2*z2v);
                float anh = acc[mt][2][r] + bhn;
                float ain = bin_ + (win0*z0v + win1*z1v + win2*z2v);
                float rg = fast_sigmoid(ar);
                float ug = fast_sigmoid(au);
                float ng = fast_tanh(ain + rg*anh);
                float hn = ng + ug*(hC[mt][r] - ng);      // (1-u)n + u h
                hC[mt][r] = hn;
                unsigned hb = bf16r(hn); float fh = bf16f(hb);
                float r1 = hn - fh;
                unsigned mb = bf16r(r1); float fm = bf16f(mb);
                unsigned lb = bf16r(r1 - fm);
                int ad = e*HS + unit;
                hbuf[p^1][0][ad] = (ushort)hb;
                hbuf[p^1][1][ad] = (ushort)mb;
                hbuf[p^1][2][ad] = (ushort)lb;
            }
        }
        __syncthreads();   // the ONLY barrier per step
    }

    // ---- epilogue: z(nsteps) needs head over h(nsteps) ----
    {
        const int p = nsteps & 1;
        f32x4 hacc[2];
        #pragma unroll
        for (int mt = 0; mt < 2; ++mt) {
            f32x4 a = {0.f,0.f,0.f,0.f};
            #pragma unroll
            for (int kk = 0; kk < 2; ++kk) {
                int ad = (mt*16 + c16)*HS + 32*kk + 8*g;
                short8 fh_ = *(const short8*)&hbuf[p][0][ad];
                short8 fm_ = *(const short8*)&hbuf[p][1][ad];
                a = __builtin_amdgcn_mfma_f32_16x16x32_bf16(fh_, HB[kk][0], a, 0,0,0);
                a = __builtin_amdgcn_mfma_f32_16x16x32_bf16(fm_, HB[kk][0], a, 0,0,0);
                a = __builtin_amdgcn_mfma_f32_16x16x32_bf16(fh_, HB[kk][1], a, 0,0,0);
            }
            hacc[mt] = a;
        }
        #pragma unroll
        for (int mt = 0; mt < 2; ++mt)
            #pragma unroll
            for (int c = 0; c < 3; ++c)
                if (w == mt && c16 == c) {
                    #pragma unroll
                    for (int r = 0; r < 4; ++r) {
                        float f = __shfl(hacc[mt][r], (l & 48) + c);
                        float bhv = (c == 0) ? bh0 : (c == 1) ? bh1 : bh2;
                        float zv = zreg[mt][r][c] + dt * (f + bhv);
                        out[(size_t)(blk*MELEM + mt*16 + 4*g + r)*T3
                            + (size_t)nsteps*3 + c] = zv;
                    }
                }
    }
}

extern "C" void kernel_launch(void* const* d_in, const int* in_sizes, int n_in,
                              void* d_out, int out_size, void* d_ws, size_t ws_size,
                              hipStream_t stream) {
    const float* z0    = (const float*)d_in[0];
    const float* dtp   = (const float*)d_in[1];
    const int*   steps = (const int*)  d_in[2];
    const float* Wih   = (const float*)d_in[3];
    const float* Whh   = (const float*)d_in[4];
    const float* bih   = (const float*)d_in[5];
    const float* bhh   = (const float*)d_in[6];
    const float* Whead = (const float*)d_in[7];
    const float* bhead = (const float*)d_in[8];
    float* out = (float*)d_out;

    const int B = in_sizes[0] / 3;          // 16384
    const int nblk = B / MELEM;             // 512 blocks x 256 threads

    hipLaunchKernelGGL(gru_mfma_kernel, dim3(nblk), dim3(256), 0, stream,
                       z0, dtp, steps, Wih, Whh, bih, bhh, Whead, bhead, out);
}

// Round 7
// 4943.340 us; speedup vs baseline: 5.9292x; 1.2441x over previous
//
#include <hip/hip_runtime.h>

typedef _Float16 f16x8 __attribute__((ext_vector_type(8)));
typedef float f32x4 __attribute__((ext_vector_type(4)));

#define LOG2E 1.44269504088896340736f
#define MELEM 32          // batch elems per block (2 M-tiles of 16)
#define HS 72             // f16 stride of h LDS rows (16B-aligned, bank-spread)
#define INV2K 4.8828125e-4f   // 2^-11
#define SC2K  2048.0f         // 2^11

__device__ __forceinline__ float fast_sigmoid(float x) {
    float t = __builtin_amdgcn_exp2f(-x * LOG2E);
    return __builtin_amdgcn_rcpf(1.f + t);
}
__device__ __forceinline__ float fast_tanh(float x) {
    float t = __builtin_amdgcn_exp2f(x * (2.f * LOG2E));
    return 1.f - 2.f * __builtin_amdgcn_rcpf(1.f + t);
}
__device__ __forceinline__ float bpermf(int sa, float v) {
    return __builtin_bit_cast(float,
        __builtin_amdgcn_ds_bpermute(sa, __builtin_bit_cast(int, v)));
}

__global__ __launch_bounds__(256, 2)
void gru_mfma_kernel(const float* __restrict__ z0,
                     const float* __restrict__ dtp,
                     const int* __restrict__ stepsp,
                     const float* __restrict__ Wih,
                     const float* __restrict__ Whh,
                     const float* __restrict__ bih,
                     const float* __restrict__ bhh,
                     const float* __restrict__ Whead,
                     const float* __restrict__ bhead,
                     float* __restrict__ out)
{
    // [pingpong][part hi/lo][elem*HS + unit], fp16 2-way split of h
    __shared__ __align__(16) _Float16 hbuf[2][2][MELEM*HS];

    const int tid = threadIdx.x;
    const int w   = tid >> 6;       // wave 0..3 -> unit range [16w,16w+16)
    const int l   = tid & 63;
    const int c16 = l & 15;
    const int g   = l >> 4;         // 0..3
    const int unit = 16*w + c16;

    const float dt = dtp[0];
    const int nsteps = stepsp[0];
    const size_t T3 = (size_t)(nsteps + 1) * 3;
    const long blk = blockIdx.x;

    // ---- B-fragments of W_hh: fp16 hi + 2^11-scaled lo ----
    // B[k][col]: col = lane&15 (unit), k = (lane>>4)*8 + j  (+32*kk)
    f16x8 WBh[3][2], WBl[3][2];   // [gate][kappa]
    #pragma unroll
    for (int gate = 0; gate < 3; ++gate) {
        const float* row = Whh + (size_t)(gate*64 + unit) * 64;
        #pragma unroll
        for (int kk = 0; kk < 2; ++kk) {
            const float* p = row + 32*kk + 8*g;
            f16x8 bh_, bl_;
            #pragma unroll
            for (int j = 0; j < 8; ++j) {
                float x = p[j];
                _Float16 hi = (_Float16)x;
                float fh = (float)hi;
                bh_[j] = hi;
                bl_[j] = (_Float16)((x - fh) * SC2K);
            }
            WBh[gate][kk] = bh_; WBl[gate][kk] = bl_;
        }
    }
    // ---- head B-fragments (all waves; cols >= 3 zero) ----
    f16x8 HBh[2], HBl[2];
    {
        f16x8 zf = {0,0,0,0,0,0,0,0};
        HBh[0]=zf; HBh[1]=zf; HBl[0]=zf; HBl[1]=zf;
        if (c16 < 3) {
            #pragma unroll
            for (int kk = 0; kk < 2; ++kk) {
                const float* p = Whead + (size_t)c16*64 + 32*kk + 8*g;
                f16x8 bh_, bl_;
                #pragma unroll
                for (int j = 0; j < 8; ++j) {
                    float x = p[j];
                    _Float16 hi = (_Float16)x;
                    float fh = (float)hi;
                    bh_[j] = hi;
                    bl_[j] = (_Float16)((x - fh) * SC2K);
                }
                HBh[kk] = bh_; HBl[kk] = bl_;
            }
        }
    }

    // ---- per-lane scalar weights / biases ----
    const float wir0 = Wih[(0*64+unit)*3+0], wir1 = Wih[(0*64+unit)*3+1], wir2 = Wih[(0*64+unit)*3+2];
    const float wiu0 = Wih[(1*64+unit)*3+0], wiu1 = Wih[(1*64+unit)*3+1], wiu2 = Wih[(1*64+unit)*3+2];
    const float win0 = Wih[(2*64+unit)*3+0], win1 = Wih[(2*64+unit)*3+1], win2 = Wih[(2*64+unit)*3+2];
    const float br   = bih[0*64+unit] + bhh[0*64+unit];
    const float bu   = bih[1*64+unit] + bhh[1*64+unit];
    const float bin_ = bih[2*64+unit];
    const float bhn  = bhh[2*64+unit];
    const float bh0 = bhead[0], bh1 = bhead[1], bh2 = bhead[2];

    // ---- z replicated in registers on every lane (all indices static) ----
    float zreg[2][4][3];
    #pragma unroll
    for (int mt = 0; mt < 2; ++mt)
        #pragma unroll
        for (int r = 0; r < 4; ++r)
            #pragma unroll
            for (int c = 0; c < 3; ++c)
                zreg[mt][r][c] = z0[(size_t)(blk*MELEM + mt*16 + 4*g + r)*3 + c];

    // ---- persistent traj cursors (designated lanes: w<2 && c16<3) ----
    float* o0 = out; float* o1 = out; float* o2 = out; float* o3 = out;
    if (w < 2 && c16 < 3) {
        size_t e0 = (size_t)(blk*MELEM + w*16 + 4*g);
        o0 = out + (e0+0)*T3 + c16;
        o1 = out + (e0+1)*T3 + c16;
        o2 = out + (e0+2)*T3 + c16;
        o3 = out + (e0+3)*T3 + c16;
    }
    // t=0 row (static zreg indices via unrolled predication)
    #pragma unroll
    for (int mt = 0; mt < 2; ++mt)
        #pragma unroll
        for (int c = 0; c < 3; ++c)
            if (w == mt && c16 == c) {
                o0[0] = zreg[mt][0][c]; o1[0] = zreg[mt][1][c];
                o2[0] = zreg[mt][2][c]; o3[0] = zreg[mt][3][c];
            }
    if (w < 2 && c16 < 3) { o0 += 3; o1 += 3; o2 += 3; o3 += 3; }  // -> t=1

    // hoisted bpermute byte-addresses (step-invariant)
    const int sa0 = ((l & 48) + 0) << 2;
    const int sa1 = ((l & 48) + 1) << 2;
    const int sa2 = ((l & 48) + 2) << 2;

    // step-invariant LDS element offsets for A-fragments
    int adA[2][2];
    #pragma unroll
    for (int mt = 0; mt < 2; ++mt)
        #pragma unroll
        for (int kk = 0; kk < 2; ++kk)
            adA[mt][kk] = (mt*16 + c16)*HS + 32*kk + 8*g;

    // ---- zero h buffer 0 (h_0 = 0) ----
    {
        uint* hz = (uint*)&hbuf[0][0][0];
        #pragma unroll
        for (int k = 0; k < (2*MELEM*HS)/(2*256); ++k) hz[tid + 256*k] = 0u;
    }

    float hC[2][4] = {{0,0,0,0},{0,0,0,0}};

    __syncthreads();

    for (int t = 0; t < nsteps; ++t) {
        const int p = t & 1, q = p ^ 1;
        const _Float16* __restrict__ bufh = &hbuf[p][0][0];
        const _Float16* __restrict__ bufl = &hbuf[p][1][0];

        // ---- 1) A-fragments of h(t) ----
        f16x8 FAh[2][2], FAl[2][2];
        #pragma unroll
        for (int mt = 0; mt < 2; ++mt)
            #pragma unroll
            for (int kk = 0; kk < 2; ++kk) {
                FAh[mt][kk] = *(const f16x8*)(bufh + adA[mt][kk]);
                FAl[mt][kk] = *(const f16x8*)(bufl + adA[mt][kk]);
            }

        // ---- 2) head GEMM over h(t) (every wave, fp16 2-way split) ----
        f32x4 h1[2], h2[2];
        #pragma unroll
        for (int mt = 0; mt < 2; ++mt) {
            f32x4 a = {0.f,0.f,0.f,0.f}, b = {0.f,0.f,0.f,0.f};
            #pragma unroll
            for (int kk = 0; kk < 2; ++kk) {
                a = __builtin_amdgcn_mfma_f32_16x16x32_f16(FAh[mt][kk], HBh[kk], a, 0,0,0);
                b = __builtin_amdgcn_mfma_f32_16x16x32_f16(FAh[mt][kk], HBl[kk], b, 0,0,0);
                b = __builtin_amdgcn_mfma_f32_16x16x32_f16(FAl[mt][kk], HBh[kk], b, 0,0,0);
            }
            h1[mt] = a; h2[mt] = b;
        }

        // ---- 3) z(t) = z(t-1) + dt*(f + bh); broadcast via bpermute; store ----
        if (t) {
            #pragma unroll
            for (int mt = 0; mt < 2; ++mt)
                #pragma unroll
                for (int r = 0; r < 4; ++r) {
                    float fv = h1[mt][r] + INV2K*h2[mt][r];
                    float f0 = bpermf(sa0, fv);
                    float f1 = bpermf(sa1, fv);
                    float f2 = bpermf(sa2, fv);
                    zreg[mt][r][0] += dt*(f0 + bh0);
                    zreg[mt][r][1] += dt*(f1 + bh1);
                    zreg[mt][r][2] += dt*(f2 + bh2);
                }
            #pragma unroll
            for (int mt = 0; mt < 2; ++mt)
                #pragma unroll
                for (int c = 0; c < 3; ++c)
                    if (w == mt && c16 == c) {
                        o0[0] = zreg[mt][0][c]; o1[0] = zreg[mt][1][c];
                        o2[0] = zreg[mt][2][c]; o3[0] = zreg[mt][3][c];
                    }
            if (w < 2 && c16 < 3) { o0 += 3; o1 += 3; o2 += 3; o3 += 3; }
        }

        // ---- 4) gates GEMM + finish, per M-tile ----
        #pragma unroll
        for (int mt = 0; mt < 2; ++mt) {
            f32x4 a1[3], a2[3];
            #pragma unroll
            for (int gate = 0; gate < 3; ++gate) {
                f32x4 z4 = {0.f,0.f,0.f,0.f};
                a1[gate] = z4; a2[gate] = z4;
            }
            #pragma unroll
            for (int kk = 0; kk < 2; ++kk)
                #pragma unroll
                for (int gate = 0; gate < 3; ++gate) {
                    a1[gate] = __builtin_amdgcn_mfma_f32_16x16x32_f16(FAh[mt][kk], WBh[gate][kk], a1[gate], 0,0,0);
                    a2[gate] = __builtin_amdgcn_mfma_f32_16x16x32_f16(FAh[mt][kk], WBl[gate][kk], a2[gate], 0,0,0);
                    a2[gate] = __builtin_amdgcn_mfma_f32_16x16x32_f16(FAl[mt][kk], WBh[gate][kk], a2[gate], 0,0,0);
                }
            #pragma unroll
            for (int r = 0; r < 4; ++r) {
                float z0v = zreg[mt][r][0], z1v = zreg[mt][r][1], z2v = zreg[mt][r][2];
                float ar  = a1[0][r] + INV2K*a2[0][r] + br  + (wir0*z0v + wir1*z1v + wir2*z2v);
                float au  = a1[1][r] + INV2K*a2[1][r] + bu  + (wiu0*z0v + wiu1*z1v + wiu2*z2v);
                float anh = a1[2][r] + INV2K*a2[2][r] + bhn;
                float ain = bin_ + (win0*z0v + win1*z1v + win2*z2v);
                float rg = fast_sigmoid(ar);
                float ug = fast_sigmoid(au);
                float ng = fast_tanh(ain + rg*anh);
                float hn = ng + ug*(hC[mt][r] - ng);      // (1-u)n + u h
                hC[mt][r] = hn;
                _Float16 hi = (_Float16)hn;
                float fh = (float)hi;
                _Float16 lo = (_Float16)((hn - fh) * SC2K);
                int ad = (mt*16 + 4*g + r)*HS + unit;
                hbuf[q][0][ad] = hi;
                hbuf[q][1][ad] = lo;
            }
        }
        __syncthreads();   // the ONLY barrier per step
    }

    // ---- epilogue: z(nsteps) from head over h(nsteps) ----
    {
        const int p = nsteps & 1;
        const _Float16* bufh = &hbuf[p][0][0];
        const _Float16* bufl = &hbuf[p][1][0];
        #pragma unroll
        for (int mt = 0; mt < 2; ++mt) {
            f32x4 a = {0.f,0.f,0.f,0.f}, b = {0.f,0.f,0.f,0.f};
            #pragma unroll
            for (int kk = 0; kk < 2; ++kk) {
                f16x8 fh_ = *(const f16x8*)(bufh + adA[mt][kk]);
                f16x8 fl_ = *(const f16x8*)(bufl + adA[mt][kk]);
                a = __builtin_amdgcn_mfma_f32_16x16x32_f16(fh_, HBh[kk], a, 0,0,0);
                b = __builtin_amdgcn_mfma_f32_16x16x32_f16(fh_, HBl[kk], b, 0,0,0);
                b = __builtin_amdgcn_mfma_f32_16x16x32_f16(fl_, HBh[kk], b, 0,0,0);
            }
            #pragma unroll
            for (int r = 0; r < 4; ++r) {
                float fv = a[r] + INV2K*b[r];
                float f0 = bpermf(sa0, fv);
                float f1 = bpermf(sa1, fv);
                float f2 = bpermf(sa2, fv);
                zreg[mt][r][0] += dt*(f0 + bh0);
                zreg[mt][r][1] += dt*(f1 + bh1);
                zreg[mt][r][2] += dt*(f2 + bh2);
            }
        }
        #pragma unroll
        for (int mt = 0; mt < 2; ++mt)
            #pragma unroll
            for (int c = 0; c < 3; ++c)
                if (w == mt && c16 == c) {
                    o0[0] = zreg[mt][0][c]; o1[0] = zreg[mt][1][c];
                    o2[0] = zreg[mt][2][c]; o3[0] = zreg[mt][3][c];
                }
    }
}

extern "C" void kernel_launch(void* const* d_in, const int* in_sizes, int n_in,
                              void* d_out, int out_size, void* d_ws, size_t ws_size,
                              hipStream_t stream) {
    const float* z0    = (const float*)d_in[0];
    const float* dtp   = (const float*)d_in[1];
    const int*   steps = (const int*)  d_in[2];
    const float* Wih   = (const float*)d_in[3];
    const float* Whh   = (const float*)d_in[4];
    const float* bih   = (const float*)d_in[5];
    const float* bhh   = (const float*)d_in[6];
    const float* Whead = (const float*)d_in[7];
    const float* bhead = (const float*)d_in[8];
    float* out = (float*)d_out;

    const int B = in_sizes[0] / 3;          // 16384
    const int nblk = B / MELEM;             // 512 blocks x 256 threads

    hipLaunchKernelGGL(gru_mfma_kernel, dim3(nblk), dim3(256), 0, stream,
                       z0, dtp, steps, Wih, Whh, bih, bhh, Whead, bhead, out);
}